// Round 8
// baseline (127.219 us; speedup 1.0000x reference)
//
#include <hip/hip_runtime.h>
#include <stdint.h>
#include <math.h>

// SACoFALoss — N=8192, A=1024, C=2.  PASSED r6/r7 (absmax 5.8e-11 = 1 bf16-ULP).
// NUMERICS FROZEN: f64 Q accumulation (any order), f32-faithful per-sample CE
// (nll_f32), dual-format bf16 store.
// r7 decomposition: dur 93.8 = ~87us harness 268MB ws-poison fills (fixed floor)
// + ~6.8us our slice (2 launches + 8.4MB CV read + serial CE tail).
// r8 change: SINGLE kernel via last-block-done. q[] accumulated with f64
// device-scope atomicAdd into d_ws (0xAA poison as f64 = -2e-103, absorbed);
// done-counter starts at poison 0xAAAAAAAA (deterministic; 0 accepted too).
// Last block re-reads q via atomic RMW (XCD-coherent) and computes CE inline.

static constexpr int kA = 1024;
static constexpr int kN = 8192;
static constexpr int kBlocks = 512;                 // 4 waves/block -> 2048 rows
static constexpr uint32_t kPoison = 0xAAAAAAAAu;

__device__ __forceinline__ void store_dual(uint32_t* out, double Ld) {
    const float L = (float)Ld;
    const uint32_t b = __float_as_uint(L);
    const uint32_t bhi = (b + 0x7FFFu + ((b >> 16) & 1u)) >> 16;  // RNE to bf16
    out[0] = (bhi << 16) | bhi;
}

// f32-faithful per-sample nll (FROZEN — reproduces np f32 log_softmax cutoff).
__device__ __forceinline__ float nll_f32(float y_t, float y_o, float hr, float q32) {
    const float aug_o = y_o + hr * q32;
    const float gap   = aug_o - y_t;
    if (gap <= 0.0f) {
        return logf(1.0f + expf(gap));
    } else {
        return gap + logf(1.0f + expf(-gap));
    }
}

// ---------- fused single kernel: quad partials + last-block CE ----------
__global__ __launch_bounds__(256) void sacofa_fused(const float* __restrict__ W,
                                                    const float* __restrict__ CV,
                                                    const float* __restrict__ y,
                                                    const int* __restrict__ tgt,
                                                    const float* __restrict__ ratio_p,
                                                    double* __restrict__ q,
                                                    uint32_t* __restrict__ cnt,
                                                    uint32_t* __restrict__ out) {
    const int tid  = (int)threadIdx.x;
    const int lane = tid & 63;
    const int wv   = tid >> 6;
    const int row  = (int)blockIdx.x * 4 + wv;        // l = row>>10, a = row&1023

    // --- stage 1: this wave's row partial, float4 loads, f64 shfl reduce ---
    const float* __restrict__ rowp = CV + ((size_t)row << 10);
    double p = 0.0;
#pragma unroll
    for (int c = 0; c < 4; ++c) {
        const int k = c * 256 + lane * 4;
        const float4 cv = *reinterpret_cast<const float4*>(rowp + k);
        const float4 w0 = *reinterpret_cast<const float4*>(W + k);
        const float4 w1 = *reinterpret_cast<const float4*>(W + kA + k);
        p += ((double)w0.x - (double)w1.x) * (double)cv.x;
        p += ((double)w0.y - (double)w1.y) * (double)cv.y;
        p += ((double)w0.z - (double)w1.z) * (double)cv.z;
        p += ((double)w0.w - (double)w1.w) * (double)cv.w;
    }
#pragma unroll
    for (int off = 32; off > 0; off >>= 1) p += __shfl_down(p, off, 64);
    if (lane == 0) {
        const int a = row & (kA - 1);
        const double da = (double)W[a] - (double)W[kA + a];
        atomicAdd(&q[row >> 10], da * p);             // poison -2e-103 absorbed
    }

    // --- completion handshake ---
    __shared__ int is_last;
    __shared__ float qf[2];
    __syncthreads();
    if (tid == 0) {
        __threadfence();                              // q-adds visible before count
        const uint32_t old = atomicAdd(cnt, 1u);
        is_last = (old == kPoison + (kBlocks - 1)) || (old == (uint32_t)(kBlocks - 1));
    }
    __syncthreads();
    if (!is_last) return;

    // --- last block: coherent q read (atomic RMW bypasses stale caches) ---
    if (tid == 0) {
        qf[0] = (float)atomicAdd(&q[0], 0.0);         // ref's sigma2 is f32
        qf[1] = (float)atomicAdd(&q[1], 0.0);
    }
    __syncthreads();
    const float q32_0 = qf[0], q32_1 = qf[1];
    const float hr = 0.5f * ratio_p[0];               // 0.25 exact

    // --- CE over 8192 samples: 16 x (float4 y = 2 samples, int2 tgt) ---
    const float4* __restrict__ Y4 = reinterpret_cast<const float4*>(y);
    const int2*   __restrict__ T2 = reinterpret_cast<const int2*>(tgt);
    double wnll = 0.0, wsum = 0.0;
#pragma unroll
    for (int s = 0; s < 16; ++s) {
        const int idx = s * 256 + tid;
        const float4 f = Y4[idx];
        const int2   t = T2[idx];
        {   // sample 2*idx
            const float yt = (t.x == 0) ? f.x : f.y;
            const float yo = (t.x == 0) ? f.y : f.x;
            const float qq = (t.x == 0) ? q32_0 : q32_1;  // UNFLIPPED: CV[t_n]
            wnll += ((t.x == 0) ? 1.0 : 0.5) * (double)nll_f32(yt, yo, hr, qq);
            wsum += (t.x == 0) ? 1.0 : 0.5;
        }
        {   // sample 2*idx+1
            const float yt = (t.y == 0) ? f.z : f.w;
            const float yo = (t.y == 0) ? f.w : f.z;
            const float qq = (t.y == 0) ? q32_0 : q32_1;
            wnll += ((t.y == 0) ? 1.0 : 0.5) * (double)nll_f32(yt, yo, hr, qq);
            wsum += (t.y == 0) ? 1.0 : 0.5;
        }
    }
#pragma unroll
    for (int off = 32; off > 0; off >>= 1) {
        wnll += __shfl_down(wnll, off, 64);
        wsum += __shfl_down(wsum, off, 64);
    }
    __shared__ double sA[4], sB[4];
    if (lane == 0) { sA[wv] = wnll; sB[wv] = wsum; }
    __syncthreads();
    if (tid == 0) {
        const double a0 = sA[0] + sA[1] + sA[2] + sA[3];
        const double b0 = sB[0] + sB[1] + sB[2] + sB[3];
        store_dual(out, a0 / b0);
    }
}

// ---------- fallback: fully fused single block, zero workspace ----------
__global__ __launch_bounds__(1024) void fused_kernel(const float* __restrict__ W,
                                                     const float* __restrict__ CV,
                                                     const float* __restrict__ y,
                                                     const int* __restrict__ tgt,
                                                     const float* __restrict__ ratio_p,
                                                     uint32_t* __restrict__ out) {
    __shared__ double dsh[kA];
    __shared__ double wred[32];
    __shared__ float qsh[2];
    const int tid = (int)threadIdx.x, lane = tid & 63, wv = tid >> 6;
    for (int i = tid; i < kA; i += 1024)
        dsh[i] = (double)W[i] - (double)W[kA + i];
    __syncthreads();
    double acc0 = 0.0, acc1 = 0.0;
    for (int row = wv; row < 2 * kA; row += 16) {
        const int l = row >> 10, a = row & (kA - 1);
        const float* __restrict__ rowp = CV + ((size_t)row << 10);
        double p = 0.0;
#pragma unroll
        for (int j = 0; j < 16; ++j)
            p += (double)rowp[lane + 64 * j] * dsh[lane + 64 * j];
        const double c = dsh[a] * p;
        if (l == 0) acc0 += c; else acc1 += c;
    }
    for (int off = 32; off > 0; off >>= 1) {
        acc0 += __shfl_down(acc0, off, 64);
        acc1 += __shfl_down(acc1, off, 64);
    }
    if (lane == 0) { wred[wv] = acc0; wred[16 + wv] = acc1; }
    __syncthreads();
    if (tid == 0) {
        double a0 = 0.0, a1 = 0.0;
        for (int i = 0; i < 16; ++i) { a0 += wred[i]; a1 += wred[16 + i]; }
        qsh[0] = (float)a0; qsh[1] = (float)a1;
    }
    __syncthreads();
    const float q32_0 = qsh[0], q32_1 = qsh[1];
    const float hr = 0.5f * ratio_p[0];
    double wnll = 0.0, wsum = 0.0;
    for (int n = tid; n < kN; n += 1024) {
        const int t = tgt[n];
        const float y0 = y[2 * n], y1 = y[2 * n + 1];
        const float yt = (t == 0) ? y0 : y1;
        const float yo = (t == 0) ? y1 : y0;
        const float qq = (t == 0) ? q32_0 : q32_1;
        const float nll = nll_f32(yt, yo, hr, qq);
        const double w = (t == 0) ? 1.0 : 0.5;
        wnll += w * (double)nll;
        wsum += w;
    }
    for (int off = 32; off > 0; off >>= 1) {
        wnll += __shfl_down(wnll, off, 64);
        wsum += __shfl_down(wsum, off, 64);
    }
    if (lane == 0) { wred[wv] = wnll; wred[16 + wv] = wsum; }
    __syncthreads();
    if (tid == 0) {
        double a0 = 0.0, a1 = 0.0;
        for (int i = 0; i < 16; ++i) { a0 += wred[i]; a1 += wred[16 + i]; }
        store_dual(out, a0 / a1);
    }
}

extern "C" void kernel_launch(void* const* d_in, const int* in_sizes, int n_in,
                              void* d_out, int out_size, void* d_ws, size_t ws_size,
                              hipStream_t stream) {
    const float* fc_weight = (const float*)d_in[0];
    // d_in[1] = features — unused by the reference computation.
    const float* y         = (const float*)d_in[2];
    const int*   target_x  = (const int*)d_in[3];
    const float* CoVar     = (const float*)d_in[4];
    const float* ratio     = (const float*)d_in[5];
    uint32_t*    out       = (uint32_t*)d_out;

    if (ws_size >= 32) {
        double*   q   = (double*)d_ws;                       // q[0], q[1]
        uint32_t* cnt = (uint32_t*)((char*)d_ws + 16);       // done-counter
        sacofa_fused<<<kBlocks, 256, 0, stream>>>(fc_weight, CoVar, y, target_x,
                                                  ratio, q, cnt, out);
    } else {
        fused_kernel<<<1, 1024, 0, stream>>>(fc_weight, CoVar, y, target_x, ratio, out);
    }
}

// Round 9
// 107.682 us; speedup vs baseline: 1.1814x; 1.1814x over previous
//
#include <hip/hip_runtime.h>
#include <stdint.h>
#include <math.h>

// SACoFALoss — N=8192, A=1024, C=2.  PASSED r6/r7/r8 numerically (5.8e-11 = 1 ULP).
// NUMERICS FROZEN: f64 Q accumulation (any order), f32-faithful per-sample CE
// (nll_f32), dual-format bf16 store.
// r8 post-mortem: fused kernel hit 50us — atomicAdd(double) is a CAS loop and
// 1024 waves contended on each of q[0]/q[1] -> CAS retry storm. Fix: distinct
// partial[row] plain stores (r7 pattern) + u32 block-done counter + last-block
// fence-acquire read + inline CE. No hot f64 atomics anywhere.

static constexpr int kA = 1024;
static constexpr int kN = 8192;
static constexpr int kBlocks = 512;                 // 4 waves/block -> 2048 rows
static constexpr uint32_t kPoison = 0xAAAAAAAAu;

__device__ __forceinline__ void store_dual(uint32_t* out, double Ld) {
    const float L = (float)Ld;
    const uint32_t b = __float_as_uint(L);
    const uint32_t bhi = (b + 0x7FFFu + ((b >> 16) & 1u)) >> 16;  // RNE to bf16
    out[0] = (bhi << 16) | bhi;
}

// f32-faithful per-sample nll (FROZEN — reproduces np f32 log_softmax cutoff).
__device__ __forceinline__ float nll_f32(float y_t, float y_o, float hr, float q32) {
    const float aug_o = y_o + hr * q32;
    const float gap   = aug_o - y_t;
    if (gap <= 0.0f) {
        return logf(1.0f + expf(gap));
    } else {
        return gap + logf(1.0f + expf(-gap));
    }
}

// ---------- fused single kernel: partials (plain stores) + last-block CE ----------
__global__ __launch_bounds__(256) void sacofa_fused(const float* __restrict__ W,
                                                    const float* __restrict__ CV,
                                                    const float* __restrict__ y,
                                                    const int* __restrict__ tgt,
                                                    const float* __restrict__ ratio_p,
                                                    double* __restrict__ partial,
                                                    uint32_t* __restrict__ cnt,
                                                    uint32_t* __restrict__ out) {
    const int tid  = (int)threadIdx.x;
    const int lane = tid & 63;
    const int wv   = tid >> 6;
    const int row  = (int)blockIdx.x * 4 + wv;        // l = row>>10, a = row&1023

    // --- stage 1: this wave's row partial, float4 loads, f64 shfl reduce ---
    const float* __restrict__ rowp = CV + ((size_t)row << 10);
    double p = 0.0;
#pragma unroll
    for (int c = 0; c < 4; ++c) {
        const int k = c * 256 + lane * 4;
        const float4 cv = *reinterpret_cast<const float4*>(rowp + k);
        const float4 w0 = *reinterpret_cast<const float4*>(W + k);
        const float4 w1 = *reinterpret_cast<const float4*>(W + kA + k);
        p += ((double)w0.x - (double)w1.x) * (double)cv.x;
        p += ((double)w0.y - (double)w1.y) * (double)cv.y;
        p += ((double)w0.z - (double)w1.z) * (double)cv.z;
        p += ((double)w0.w - (double)w1.w) * (double)cv.w;
    }
#pragma unroll
    for (int off = 32; off > 0; off >>= 1) p += __shfl_down(p, off, 64);
    if (lane == 0) {
        const int a = row & (kA - 1);
        const double da = (double)W[a] - (double)W[kA + a];
        partial[row] = da * p;                        // DISTINCT address: plain store
    }

    // --- completion handshake: release fence + one u32 atomic per block ---
    __shared__ int is_last;
    __shared__ float qf[2];
    __syncthreads();
    if (tid == 0) {
        __threadfence();                              // release: wb dirty L2 lines
        const uint32_t old = atomicAdd(cnt, 1u);
        is_last = (old == kPoison + (kBlocks - 1)) || (old == (uint32_t)(kBlocks - 1));
    }
    __syncthreads();
    if (!is_last) return;
    __threadfence();                                  // acquire: invalidate stale caches

    // --- last block: sum partials (plain loads, 8/thread/class), f64 any-order ---
    double s0 = 0.0, s1 = 0.0;
#pragma unroll
    for (int c = 0; c < 4; ++c) {
        s0 += partial[c * 256 + tid];
        s1 += partial[kA + c * 256 + tid];
    }
#pragma unroll
    for (int off = 32; off > 0; off >>= 1) {
        s0 += __shfl_down(s0, off, 64);
        s1 += __shfl_down(s1, off, 64);
    }
    __shared__ double sA[4], sB[4];
    if (lane == 0) { sA[wv] = s0; sB[wv] = s1; }
    __syncthreads();
    if (tid == 0) {
        qf[0] = (float)(sA[0] + sA[1] + sA[2] + sA[3]);   // ref's sigma2 is f32
        qf[1] = (float)(sB[0] + sB[1] + sB[2] + sB[3]);
    }
    __syncthreads();
    const float q32_0 = qf[0], q32_1 = qf[1];
    const float hr = 0.5f * ratio_p[0];               // 0.25 exact

    // --- CE over 8192 samples: 16 x (float4 y = 2 samples, int2 tgt) ---
    const float4* __restrict__ Y4 = reinterpret_cast<const float4*>(y);
    const int2*   __restrict__ T2 = reinterpret_cast<const int2*>(tgt);
    double wnll = 0.0, wsum = 0.0;
#pragma unroll
    for (int s = 0; s < 16; ++s) {
        const int idx = s * 256 + tid;
        const float4 f = Y4[idx];
        const int2   t = T2[idx];
        {   // sample 2*idx
            const float yt = (t.x == 0) ? f.x : f.y;
            const float yo = (t.x == 0) ? f.y : f.x;
            const float qq = (t.x == 0) ? q32_0 : q32_1;  // UNFLIPPED: CV[t_n]
            wnll += ((t.x == 0) ? 1.0 : 0.5) * (double)nll_f32(yt, yo, hr, qq);
            wsum += (t.x == 0) ? 1.0 : 0.5;
        }
        {   // sample 2*idx+1
            const float yt = (t.y == 0) ? f.z : f.w;
            const float yo = (t.y == 0) ? f.w : f.z;
            const float qq = (t.y == 0) ? q32_0 : q32_1;
            wnll += ((t.y == 0) ? 1.0 : 0.5) * (double)nll_f32(yt, yo, hr, qq);
            wsum += (t.y == 0) ? 1.0 : 0.5;
        }
    }
#pragma unroll
    for (int off = 32; off > 0; off >>= 1) {
        wnll += __shfl_down(wnll, off, 64);
        wsum += __shfl_down(wsum, off, 64);
    }
    if (lane == 0) { sA[wv] = wnll; sB[wv] = wsum; }
    __syncthreads();
    if (tid == 0) {
        const double a0 = sA[0] + sA[1] + sA[2] + sA[3];
        const double b0 = sB[0] + sB[1] + sB[2] + sB[3];
        store_dual(out, a0 / b0);
    }
}

// ---------- fallback: fully fused single block, zero workspace ----------
__global__ __launch_bounds__(1024) void fused_kernel(const float* __restrict__ W,
                                                     const float* __restrict__ CV,
                                                     const float* __restrict__ y,
                                                     const int* __restrict__ tgt,
                                                     const float* __restrict__ ratio_p,
                                                     uint32_t* __restrict__ out) {
    __shared__ double dsh[kA];
    __shared__ double wred[32];
    __shared__ float qsh[2];
    const int tid = (int)threadIdx.x, lane = tid & 63, wv = tid >> 6;
    for (int i = tid; i < kA; i += 1024)
        dsh[i] = (double)W[i] - (double)W[kA + i];
    __syncthreads();
    double acc0 = 0.0, acc1 = 0.0;
    for (int row = wv; row < 2 * kA; row += 16) {
        const int l = row >> 10, a = row & (kA - 1);
        const float* __restrict__ rowp = CV + ((size_t)row << 10);
        double p = 0.0;
#pragma unroll
        for (int j = 0; j < 16; ++j)
            p += (double)rowp[lane + 64 * j] * dsh[lane + 64 * j];
        const double c = dsh[a] * p;
        if (l == 0) acc0 += c; else acc1 += c;
    }
    for (int off = 32; off > 0; off >>= 1) {
        acc0 += __shfl_down(acc0, off, 64);
        acc1 += __shfl_down(acc1, off, 64);
    }
    if (lane == 0) { wred[wv] = acc0; wred[16 + wv] = acc1; }
    __syncthreads();
    if (tid == 0) {
        double a0 = 0.0, a1 = 0.0;
        for (int i = 0; i < 16; ++i) { a0 += wred[i]; a1 += wred[16 + i]; }
        qsh[0] = (float)a0; qsh[1] = (float)a1;
    }
    __syncthreads();
    const float q32_0 = qsh[0], q32_1 = qsh[1];
    const float hr = 0.5f * ratio_p[0];
    double wnll = 0.0, wsum = 0.0;
    for (int n = tid; n < kN; n += 1024) {
        const int t = tgt[n];
        const float y0 = y[2 * n], y1 = y[2 * n + 1];
        const float yt = (t == 0) ? y0 : y1;
        const float yo = (t == 0) ? y1 : y0;
        const float qq = (t == 0) ? q32_0 : q32_1;
        const float nll = nll_f32(yt, yo, hr, qq);
        const double w = (t == 0) ? 1.0 : 0.5;
        wnll += w * (double)nll;
        wsum += w;
    }
    for (int off = 32; off > 0; off >>= 1) {
        wnll += __shfl_down(wnll, off, 64);
        wsum += __shfl_down(wsum, off, 64);
    }
    if (lane == 0) { wred[wv] = wnll; wred[16 + wv] = wsum; }
    __syncthreads();
    if (tid == 0) {
        double a0 = 0.0, a1 = 0.0;
        for (int i = 0; i < 16; ++i) { a0 += wred[i]; a1 += wred[16 + i]; }
        store_dual(out, a0 / a1);
    }
}

extern "C" void kernel_launch(void* const* d_in, const int* in_sizes, int n_in,
                              void* d_out, int out_size, void* d_ws, size_t ws_size,
                              hipStream_t stream) {
    const float* fc_weight = (const float*)d_in[0];
    // d_in[1] = features — unused by the reference computation.
    const float* y         = (const float*)d_in[2];
    const int*   target_x  = (const int*)d_in[3];
    const float* CoVar     = (const float*)d_in[4];
    const float* ratio     = (const float*)d_in[5];
    uint32_t*    out       = (uint32_t*)d_out;

    if (ws_size >= 2 * kA * sizeof(double) + sizeof(uint32_t)) {
        double*   partial = (double*)d_ws;                       // 2048 f64 (16 KB)
        uint32_t* cnt     = (uint32_t*)((char*)d_ws + 2 * kA * sizeof(double));
        sacofa_fused<<<kBlocks, 256, 0, stream>>>(fc_weight, CoVar, y, target_x,
                                                  ratio, partial, cnt, out);
    } else {
        fused_kernel<<<1, 1024, 0, stream>>>(fc_weight, CoVar, y, target_x, ratio, out);
    }
}

// Round 11
// 92.534 us; speedup vs baseline: 1.3748x; 1.1637x over previous
//
#include <hip/hip_runtime.h>
#include <stdint.h>
#include <math.h>

// SACoFALoss — N=8192, A=1024, C=2.  r7 structure (best measured: 93.8us).
// (r10 was a GPU-acquisition infra failure; this source was never benched.)
// NUMERICS FROZEN: f64 Q accumulation (any order), f32-faithful per-sample CE
// (nll_f32), dual-format bf16 store.
// Session ledger: r8 fused + f64 atomicAdd(q[0/1]) = CAS storm (kernel 50us).
// r9 fused + plain stores + fence/counter handshake = fence serialization
// (~20us slice; dur 107.7). r7 two-kernel split = ~7us slice (dur 93.8).
// => kernel-boundary sync beats a 512-block fence handshake here. Final
// structure: stage1 wave-per-row (512x256), stage2 single 1024-thread block.
// dur floor decomposition: ~87us harness 268MB ws-poison fills @6.2TB/s
// (HBM-ceiling, fixed) + ~1.4us mandatory CV read + ~4us launches + CE tail.

static constexpr int kA = 1024;
static constexpr int kN = 8192;

__device__ __forceinline__ void store_dual(uint32_t* out, double Ld) {
    const float L = (float)Ld;
    const uint32_t b = __float_as_uint(L);
    const uint32_t bhi = (b + 0x7FFFu + ((b >> 16) & 1u)) >> 16;  // RNE to bf16
    out[0] = (bhi << 16) | bhi;
}

// f32-faithful per-sample nll (FROZEN — reproduces np f32 log_softmax cutoff).
__device__ __forceinline__ float nll_f32(float y_t, float y_o, float hr, float q32) {
    const float aug_o = y_o + hr * q32;
    const float gap   = aug_o - y_t;
    if (gap <= 0.0f) {
        return logf(1.0f + expf(gap));
    } else {
        return gap + logf(1.0f + expf(-gap));
    }
}

// ---------- stage 1: one WAVE per CV row; partial[row] = d[a] * (CV[row].d) ----------
// 512 blocks x 256 thr = 2048 waves. float4 loads; f64 shfl butterfly; no LDS.
__global__ __launch_bounds__(256) void quad_partial(const float* __restrict__ W,
                                                    const float* __restrict__ CV,
                                                    double* __restrict__ partial) {
    const int tid  = (int)threadIdx.x;
    const int lane = tid & 63;
    const int row  = (int)blockIdx.x * 4 + (tid >> 6);       // l = row>>10, a = row&1023
    const float* __restrict__ rowp = CV + ((size_t)row << 10);
    double p = 0.0;
#pragma unroll
    for (int c = 0; c < 4; ++c) {
        const int k = c * 256 + lane * 4;                     // coalesced 1KB/wave/instr
        const float4 cv = *reinterpret_cast<const float4*>(rowp + k);
        const float4 w0 = *reinterpret_cast<const float4*>(W + k);
        const float4 w1 = *reinterpret_cast<const float4*>(W + kA + k);
        p += ((double)w0.x - (double)w1.x) * (double)cv.x;
        p += ((double)w0.y - (double)w1.y) * (double)cv.y;
        p += ((double)w0.z - (double)w1.z) * (double)cv.z;
        p += ((double)w0.w - (double)w1.w) * (double)cv.w;
    }
#pragma unroll
    for (int off = 32; off > 0; off >>= 1) p += __shfl_down(p, off, 64);
    if (lane == 0) {
        const int a = row & (kA - 1);
        const double da = (double)W[a] - (double)W[kA + a];
        partial[row] = da * p;
    }
}

// ---------- stage 2: single block, 1024 thr (16 waves); Q-sum + f32-CE ----------
__global__ __launch_bounds__(1024) void loss_kernel(const double* __restrict__ partial,
                                                    const float* __restrict__ y,
                                                    const int* __restrict__ tgt,
                                                    const float* __restrict__ ratio_p,
                                                    uint32_t* __restrict__ out) {
    const int tid  = (int)threadIdx.x;
    const int lane = tid & 63;
    const int wv   = tid >> 6;                                // 16 waves
    __shared__ double sA[16], sB[16];
    __shared__ float  qf[2];

    // Q sums: one partial element per thread per class.
    double s0 = partial[tid], s1 = partial[kA + tid];
#pragma unroll
    for (int off = 32; off > 0; off >>= 1) {
        s0 += __shfl_down(s0, off, 64);
        s1 += __shfl_down(s1, off, 64);
    }
    if (lane == 0) { sA[wv] = s0; sB[wv] = s1; }
    __syncthreads();
    if (tid == 0) {
        double a0 = 0.0, a1 = 0.0;
#pragma unroll
        for (int i = 0; i < 16; ++i) { a0 += sA[i]; a1 += sB[i]; }
        qf[0] = (float)a0; qf[1] = (float)a1;                 // ref's sigma2 is f32
    }
    __syncthreads();
    const float q32_0 = qf[0], q32_1 = qf[1];
    const float hr = 0.5f * ratio_p[0];
    __syncthreads();                                           // sA/sB reuse below

    // CE: 8 samples per thread, vectorized (4x float4 y, 2x int4 tgt).
    const float4* __restrict__ Y4 = reinterpret_cast<const float4*>(y);
    const int4*   __restrict__ T4 = reinterpret_cast<const int4*>(tgt);
    float yv[16];
    int   tv[8];
#pragma unroll
    for (int c = 0; c < 4; ++c) {
        const float4 f = Y4[4 * tid + c];
        yv[4 * c + 0] = f.x; yv[4 * c + 1] = f.y; yv[4 * c + 2] = f.z; yv[4 * c + 3] = f.w;
    }
#pragma unroll
    for (int c = 0; c < 2; ++c) {
        const int4 t4 = T4[2 * tid + c];
        tv[4 * c + 0] = t4.x; tv[4 * c + 1] = t4.y; tv[4 * c + 2] = t4.z; tv[4 * c + 3] = t4.w;
    }
    double wnll = 0.0, wsum = 0.0;
#pragma unroll
    for (int s = 0; s < 8; ++s) {
        const int   t  = tv[s];
        const float y0 = yv[2 * s], y1 = yv[2 * s + 1];
        const float yt = (t == 0) ? y0 : y1;
        const float yo = (t == 0) ? y1 : y0;
        const float qq = (t == 0) ? q32_0 : q32_1;            // UNFLIPPED: CV[t_n]
        const float nll = nll_f32(yt, yo, hr, qq);
        const double w = (t == 0) ? 1.0 : 0.5;
        wnll += w * (double)nll;
        wsum += w;
    }
#pragma unroll
    for (int off = 32; off > 0; off >>= 1) {
        wnll += __shfl_down(wnll, off, 64);
        wsum += __shfl_down(wsum, off, 64);
    }
    if (lane == 0) { sA[wv] = wnll; sB[wv] = wsum; }
    __syncthreads();
    if (tid == 0) {
        double a0 = 0.0, a1 = 0.0;
#pragma unroll
        for (int i = 0; i < 16; ++i) { a0 += sA[i]; a1 += sB[i]; }
        store_dual(out, a0 / a1);
    }
}

// ---------- fallback: fully fused single block, zero workspace ----------
__global__ __launch_bounds__(1024) void fused_kernel(const float* __restrict__ W,
                                                     const float* __restrict__ CV,
                                                     const float* __restrict__ y,
                                                     const int* __restrict__ tgt,
                                                     const float* __restrict__ ratio_p,
                                                     uint32_t* __restrict__ out) {
    __shared__ double dsh[kA];
    __shared__ double wred[32];
    __shared__ float qsh[2];
    const int tid = (int)threadIdx.x, lane = tid & 63, wv = tid >> 6;
    for (int i = tid; i < kA; i += 1024)
        dsh[i] = (double)W[i] - (double)W[kA + i];
    __syncthreads();
    double acc0 = 0.0, acc1 = 0.0;
    for (int row = wv; row < 2 * kA; row += 16) {
        const int l = row >> 10, a = row & (kA - 1);
        const float* __restrict__ rowp = CV + ((size_t)row << 10);
        double p = 0.0;
#pragma unroll
        for (int j = 0; j < 16; ++j)
            p += (double)rowp[lane + 64 * j] * dsh[lane + 64 * j];
        const double c = dsh[a] * p;
        if (l == 0) acc0 += c; else acc1 += c;
    }
    for (int off = 32; off > 0; off >>= 1) {
        acc0 += __shfl_down(acc0, off, 64);
        acc1 += __shfl_down(acc1, off, 64);
    }
    if (lane == 0) { wred[wv] = acc0; wred[16 + wv] = acc1; }
    __syncthreads();
    if (tid == 0) {
        double a0 = 0.0, a1 = 0.0;
        for (int i = 0; i < 16; ++i) { a0 += wred[i]; a1 += wred[16 + i]; }
        qsh[0] = (float)a0; qsh[1] = (float)a1;
    }
    __syncthreads();
    const float q32_0 = qsh[0], q32_1 = qsh[1];
    const float hr = 0.5f * ratio_p[0];
    double wnll = 0.0, wsum = 0.0;
    for (int n = tid; n < kN; n += 1024) {
        const int t = tgt[n];
        const float y0 = y[2 * n], y1 = y[2 * n + 1];
        const float yt = (t == 0) ? y0 : y1;
        const float yo = (t == 0) ? y1 : y0;
        const float qq = (t == 0) ? q32_0 : q32_1;
        const float nll = nll_f32(yt, yo, hr, qq);
        const double w = (t == 0) ? 1.0 : 0.5;
        wnll += w * (double)nll;
        wsum += w;
    }
    for (int off = 32; off > 0; off >>= 1) {
        wnll += __shfl_down(wnll, off, 64);
        wsum += __shfl_down(wsum, off, 64);
    }
    if (lane == 0) { wred[wv] = wnll; wred[16 + wv] = wsum; }
    __syncthreads();
    if (tid == 0) {
        double a0 = 0.0, a1 = 0.0;
        for (int i = 0; i < 16; ++i) { a0 += wred[i]; a1 += wred[16 + i]; }
        store_dual(out, a0 / a1);
    }
}

extern "C" void kernel_launch(void* const* d_in, const int* in_sizes, int n_in,
                              void* d_out, int out_size, void* d_ws, size_t ws_size,
                              hipStream_t stream) {
    const float* fc_weight = (const float*)d_in[0];
    // d_in[1] = features — unused by the reference computation.
    const float* y         = (const float*)d_in[2];
    const int*   target_x  = (const int*)d_in[3];
    const float* CoVar     = (const float*)d_in[4];
    const float* ratio     = (const float*)d_in[5];
    uint32_t*    out       = (uint32_t*)d_out;

    if (ws_size >= 2 * kA * sizeof(double)) {
        double* partial = (double*)d_ws;
        quad_partial<<<512, 256, 0, stream>>>(fc_weight, CoVar, partial);
        loss_kernel<<<1, 1024, 0, stream>>>(partial, y, target_x, ratio, out);
    } else {
        fused_kernel<<<1, 1024, 0, stream>>>(fc_weight, CoVar, y, target_x, ratio, out);
    }
}